// Round 13
// baseline (3603.139 us; speedup 1.0000x reference)
//
#include <hip/hip_runtime.h>

// Problem dims (fixed by setup_inputs): T=256, B=64, I=512, H=2048
#define T_DIM 256
#define B_DIM 64
#define I_DIM 512
#define H_DIM 2048
#define BH (B_DIM * H_DIM)      // 131072 floats per timestep slice
#define NBLK 256                // persistent grid: 1 block per CU
#define PUB_PAR_U64 65536       // one parity: 2048k x 64b u32 = 512 KB

typedef __attribute__((ext_vector_type(8))) short bf16x8;
typedef __attribute__((ext_vector_type(4))) float f32x4;

// ---------------------------------------------------------------------
// Agent-scope ops (validated R4-R12): relaxed sc-bit global ops serviced
// at the device coherence point — coherent, uncached, no fences. R12
// proved pub-style rewritten addresses MUST use these (normal loads
// regressed via L2 first-touch misses + stale-line hazards).
// ---------------------------------------------------------------------
__device__ __forceinline__ unsigned long long aload64(
    const unsigned long long* p) {
  return __hip_atomic_load(p, __ATOMIC_RELAXED, __HIP_MEMORY_SCOPE_AGENT);
}
__device__ __forceinline__ void astoreU(unsigned long long* p,
                                        unsigned long long v) {
  __hip_atomic_store(p, v, __ATOMIC_RELAXED, __HIP_MEMORY_SCOPE_AGENT);
}
__device__ __forceinline__ void astore4(float* p, float a) {
  union { unsigned u; float f; } c; c.f = a;
  __hip_atomic_store((unsigned*)p, c.u, __ATOMIC_RELAXED,
                     __HIP_MEMORY_SCOPE_AGENT);
}

// bf16 helpers
__device__ __forceinline__ unsigned bf16_rne(float x) {
  union { float f; unsigned u; } c; c.f = x;
  return (c.u + 0x7FFFu + ((c.u >> 16) & 1u)) >> 16;
}
__device__ __forceinline__ float bf16_to_f(unsigned b) {
  union { float f; unsigned u; } c; c.u = b << 16; return c.f;
}
__device__ __forceinline__ void cvt_pair(float x0, float x1,
                                         unsigned& hi, unsigned& lo) {
  unsigned h0 = bf16_rne(x0), h1 = bf16_rne(x1);
  float r0 = x0 - bf16_to_f(h0), r1 = x1 - bf16_to_f(h1);
  unsigned l0 = bf16_rne(r0), l1 = bf16_rne(r1);
  hi = h0 | (h1 << 16);
  lo = l0 | (l1 << 16);
}
__device__ __forceinline__ void cvt8(const float* s, uint4& hi, uint4& lo) {
  float4 a = *(const float4*)s;
  float4 b = *(const float4*)(s + 4);
  cvt_pair(a.x, a.y, hi.x, lo.x);
  cvt_pair(a.z, a.w, hi.y, lo.y);
  cvt_pair(b.x, b.y, hi.z, lo.z);
  cvt_pair(b.z, b.w, hi.w, lo.w);
}

// =====================================================================
// Kernel A: xin = x @ W_ih^T + b_ih + b_hh  (rows m<64 fold t=0:
// out[0] = 0.01*relu(xin[0])).  Unchanged (fp32 VALU).
// =====================================================================
__global__ __launch_bounds__(256) void xin_gemm(
    const float* __restrict__ x, const float* __restrict__ Wih,
    const float* __restrict__ bih, const float* __restrict__ bhh,
    float* __restrict__ out)
{
  __shared__ __align__(16) float As[16][132];
  __shared__ __align__(16) float Bs[16][132];
  const int tid = threadIdx.x;
  const int nb = blockIdx.x & 15, mb = blockIdx.x >> 4;
  const int m0 = mb * 128, n0 = nb * 128;
  const int tx = tid & 15, ty = tid >> 4;

  float acc[8][8];
  #pragma unroll
  for (int i = 0; i < 8; ++i)
    #pragma unroll
    for (int j = 0; j < 8; ++j) acc[i][j] = 0.f;

  for (int k0 = 0; k0 < I_DIM; k0 += 16) {
    __syncthreads();
    {
      const int r = tid >> 1;
      #pragma unroll
      for (int c = 0; c < 2; ++c) {
        const int kq = (tid & 1) * 4 + c * 8;
        float4 va = *(const float4*)&x[(size_t)(m0 + r) * I_DIM + k0 + kq];
        As[kq + 0][r] = va.x; As[kq + 1][r] = va.y;
        As[kq + 2][r] = va.z; As[kq + 3][r] = va.w;
        float4 vb = *(const float4*)&Wih[(size_t)(n0 + r) * I_DIM + k0 + kq];
        Bs[kq + 0][r] = vb.x; Bs[kq + 1][r] = vb.y;
        Bs[kq + 2][r] = vb.z; Bs[kq + 3][r] = vb.w;
      }
    }
    __syncthreads();
    #pragma unroll 4
    for (int k = 0; k < 16; ++k) {
      float a[8], b[8];
      *(float4*)&a[0] = *(const float4*)&As[k][ty * 8];
      *(float4*)&a[4] = *(const float4*)&As[k][ty * 8 + 4];
      *(float4*)&b[0] = *(const float4*)&Bs[k][tx * 4];
      *(float4*)&b[4] = *(const float4*)&Bs[k][64 + tx * 4];
      #pragma unroll
      for (int i = 0; i < 8; ++i)
        #pragma unroll
        for (int j = 0; j < 8; ++j) acc[i][j] += a[i] * b[j];
    }
  }

  float bb[8];
  #pragma unroll
  for (int j = 0; j < 4; ++j) {
    bb[j]     = bih[n0 + tx * 4 + j]      + bhh[n0 + tx * 4 + j];
    bb[4 + j] = bih[n0 + 64 + tx * 4 + j] + bhh[n0 + 64 + tx * 4 + j];
  }
  #pragma unroll
  for (int i = 0; i < 8; ++i) {
    const int m = m0 + ty * 8 + i;
    float v[8];
    #pragma unroll
    for (int j = 0; j < 8; ++j) v[j] = acc[i][j] + bb[j];
    if (m < B_DIM) {
      #pragma unroll
      for (int j = 0; j < 8; ++j) v[j] = 0.01f * fmaxf(v[j], 0.f);
    }
    *(float4*)&out[(size_t)m * H_DIM + n0 + tx * 4] =
        make_float4(v[0], v[1], v[2], v[3]);
    *(float4*)&out[(size_t)m * H_DIM + n0 + 64 + tx * 4] =
        make_float4(v[4], v[5], v[6], v[7]);
  }
}

// =====================================================================
// Kernel B (R13): EPOCH-IN-DATA self-timed scan. 256 blocks x 512 thr
// (8 waves, 2/SIMD). Block (bh,nb) owns b in [bh*32,+32), n in
// [nb*16,+16), full K=2048; wave wid covers k in [wid*256,+256).
//
// pub[parity][ko*512 + b*8 + (k&7)] : u32 = (bf16(h)<<16) | epoch16,
// parity = step%3 (triple buffer), epoch of h[s] = s+1. Producers just
// astore their region — NO drain, NO flag. Consumers speculatively load
// all 64 u64/lane, validate every embedded epoch == t in-register, and
// re-issue the batch if any producer hasn't landed (self-timed).
// Anti-overrun: writer of buf[p] at step t+2 must have consumed epoch
// t+2 data, which needs ALL peers (incl. slowest) past publish of t+1
// -> no readable buffer is ever overwritten. Stale epochs across graph
// replays: pub memset to 0 every launch.
// W slice (16n x 2048k, split-bf16 hi+lo) in LDS (128 KB) forever.
// =====================================================================
__global__ __launch_bounds__(512) void ctrnn_scan(
    const float* __restrict__ Whh, float* out,
    unsigned long long* __restrict__ pub)
{
  __shared__ __align__(16) uint4 Whi[4096];   // 64 KB
  __shared__ __align__(16) uint4 Wlo[4096];   // 64 KB
  __shared__ __align__(16) f32x4 Red[1024];   // 16 KB (8 waves x 2 tiles)
  __shared__ unsigned Hs32[32][16];           // 2 KB publish staging

  const int tid = threadIdx.x, bid = blockIdx.x;
  const int nb = bid & 127, bh = bid >> 7;
  const int n0 = nb * 16, b0 = bh * 32;
  const int lane = tid & 63, wid = tid >> 6;      // wid 0..7
  const int fq = lane >> 4, fr = lane & 15;

  // ---- stage W slice ONCE: rows n0..n0+16, all k, frag-packed hi/lo ----
  for (int s = tid; s < 4096; s += 512) {
    const int kcg = s >> 6, l = s & 63;
    const int n = n0 + (l & 15), k = kcg * 32 + (l >> 4) * 8;
    uint4 hi, lo;
    cvt8(&Whh[(size_t)n * H_DIM + k], hi, lo);
    Whi[s] = hi; Wlo[s] = lo;
  }

  // ---- per-thread output ownership (1 elem): matches MFMA C layout ----
  const int jj = tid & 3, lane6 = (tid >> 2) & 63, tilo = tid >> 8;
  const int b_l = tilo * 16 + ((lane6 >> 4) << 2) + jj;   // 0..31
  const int n_l = lane6 & 15;
  const size_t oa = (size_t)(b0 + b_l) * H_DIM + n0 + n_l;

  // fp32 h state (h[0] = out[0], t=0 folded in xin_gemm); normal load OK
  float h = out[oa];

  // ---- publish h[0] (epoch 1) to parity 0 via LDS restage ----
  Hs32[b_l][n_l] = (bf16_rne(h) << 16) | 1u;
  __syncthreads();   // covers W staging + Hs32
  if (tid < 128) {
    const int f = tid >> 1, half = tid & 1;
    const int kol = f >> 5, bl = f & 31;
    const unsigned* src = &Hs32[bl][kol * 8 + half * 4];
    unsigned long long w0 =
        (unsigned long long)src[0] | ((unsigned long long)src[1] << 32);
    unsigned long long w1 =
        (unsigned long long)src[2] | ((unsigned long long)src[3] << 32);
    const size_t du =
        (size_t)(nb * 2 + kol) * 256 + (size_t)(b0 + bl) * 4 + half * 2;
    astoreU(&pub[du], w0);
    astoreU(&pub[du + 1], w1);
  }

  // consumer base (u64 idx in a parity): ko = wid*32 + kc*4 + fq
  const size_t cb0 = (size_t)(wid * 32 + fq) * 256 + (size_t)(b0 + fr) * 4;

  for (int t = 1; t < T_DIM; ++t) {
    const float xin = out[(size_t)t * BH + oa];  // touch-once normal load
    asm volatile("" :: "v"(xin));

    const unsigned long long* pr = pub + (size_t)((t - 1) % 3) * PUB_PAR_U64;
    const unsigned long long exp2 =
        (unsigned long long)(unsigned)t |
        ((unsigned long long)(unsigned)t << 32);

    // ---- speculative batch load + epoch validation (retry until set) ----
    unsigned long long r0[8][4], r1[8][4];
    unsigned long long diff;
    int tries = 0;
    do {
      #pragma unroll
      for (int kc = 0; kc < 8; ++kc) {
        const size_t a0 = cb0 + (size_t)kc * 1024;
        #pragma unroll
        for (int p = 0; p < 4; ++p) {
          r0[kc][p] = aload64(pr + a0 + p);
          r1[kc][p] = aload64(pr + a0 + 64 + p);
        }
      }
      diff = 0;
      #pragma unroll
      for (int kc = 0; kc < 8; ++kc)
        #pragma unroll
        for (int p = 0; p < 4; ++p)
          diff |= (r0[kc][p] ^ exp2) | (r1[kc][p] ^ exp2);
      diff &= 0x0000FFFF0000FFFFull;
    } while (diff != 0ull && ++tries < (1 << 14));

    // ---- assemble bf16 frags (strip epochs) + MFMA ----
    f32x4 acc0 = {0.f, 0.f, 0.f, 0.f}, acc1 = {0.f, 0.f, 0.f, 0.f};
    #pragma unroll
    for (int kc = 0; kc < 8; ++kc) {
      union { unsigned w[4]; bf16x8 v; } A0, A1;
      #pragma unroll
      for (int p = 0; p < 4; ++p) {
        const unsigned x0 = (unsigned)r0[kc][p];
        const unsigned x1 = (unsigned)(r0[kc][p] >> 32);
        A0.w[p] = (x1 & 0xFFFF0000u) | (x0 >> 16);
        const unsigned y0 = (unsigned)r1[kc][p];
        const unsigned y1 = (unsigned)(r1[kc][p] >> 32);
        A1.w[p] = (y1 & 0xFFFF0000u) | (y0 >> 16);
      }
      const uint4 bhv = Whi[(wid * 8 + kc) * 64 + lane];
      const uint4 blv = Wlo[(wid * 8 + kc) * 64 + lane];
      acc0 = __builtin_amdgcn_mfma_f32_16x16x32_bf16(
          A0.v, *(const bf16x8*)&bhv, acc0, 0, 0, 0);
      acc0 = __builtin_amdgcn_mfma_f32_16x16x32_bf16(
          A0.v, *(const bf16x8*)&blv, acc0, 0, 0, 0);
      acc1 = __builtin_amdgcn_mfma_f32_16x16x32_bf16(
          A1.v, *(const bf16x8*)&bhv, acc1, 0, 0, 0);
      acc1 = __builtin_amdgcn_mfma_f32_16x16x32_bf16(
          A1.v, *(const bf16x8*)&blv, acc1, 0, 0, 0);
    }

    // ---- cross-wave K reduce (8 waves) ----
    Red[(wid * 2 + 0) * 64 + lane] = acc0;
    Red[(wid * 2 + 1) * 64 + lane] = acc1;
    __syncthreads();

    float s = 0.f;
    #pragma unroll
    for (int w = 0; w < 8; ++w)
      s += *(const float*)((const char*)&Red[(w * 2 + tilo) * 64 + lane6] +
                           jj * 4);

    // ---- leaky-relu update (fp32 register state) ----
    h = 0.99f * h + 0.01f * fmaxf(xin + s, 0.f);

    // ---- out store + publish h[t] (epoch t+1) to parity t%3 ----
    astore4(&out[(size_t)t * BH + oa], h);
    if (t == T_DIM - 1)
      astore4(&out[(size_t)T_DIM * BH + oa], h);   // h_last

    Hs32[b_l][n_l] = (bf16_rne(h) << 16) | (unsigned)(t + 1);
    __syncthreads();
    if (t < T_DIM - 1 && tid < 128) {
      const int f = tid >> 1, half = tid & 1;
      const int kol = f >> 5, bl = f & 31;
      const unsigned* src = &Hs32[bl][kol * 8 + half * 4];
      unsigned long long w0 =
          (unsigned long long)src[0] | ((unsigned long long)src[1] << 32);
      unsigned long long w1 =
          (unsigned long long)src[2] | ((unsigned long long)src[3] << 32);
      unsigned long long* pw =
          pub + (size_t)(t % 3) * PUB_PAR_U64 +
          (size_t)(nb * 2 + kol) * 256 + (size_t)(b0 + bl) * 4 + half * 2;
      astoreU(pw + 0, w0);
      astoreU(pw + 1, w1);
    }
    // no drain, no flag — consumers self-time on embedded epochs
  }
}

// =====================================================================
extern "C" void kernel_launch(void* const* d_in, const int* in_sizes, int n_in,
                              void* d_out, int out_size, void* d_ws, size_t ws_size,
                              hipStream_t stream) {
  const float* x    = (const float*)d_in[0];
  const float* Wih  = (const float*)d_in[1];
  const float* bih  = (const float*)d_in[2];
  const float* Whh  = (const float*)d_in[3];
  const float* bhh  = (const float*)d_in[4];
  float* out = (float*)d_out;

  unsigned long long* pub =
      (unsigned long long*)((char*)d_ws + 32768);   // 3 x 512 KB

  // zero epochs every launch (covers graph replays; serialized on stream)
  hipMemsetAsync(d_ws, 0, 32768 + 3 * 524288, stream);

  xin_gemm<<<dim3(2048), dim3(256), 0, stream>>>(x, Wih, bih, bhh, out);
  ctrnn_scan<<<dim3(NBLK), dim3(512), 0, stream>>>(Whh, out, pub);
}

// Round 14
// 1397.902 us; speedup vs baseline: 2.5775x; 2.5775x over previous
//
#include <hip/hip_runtime.h>

// Problem dims (fixed by setup_inputs): T=256, B=64, I=512, H=2048
#define T_DIM 256
#define B_DIM 64
#define I_DIM 512
#define H_DIM 2048
#define BH (B_DIM * H_DIM)      // 131072 floats per timestep slice
#define NBLK 256                // persistent grid: 1 block per CU
#define PUB_U64 32768           // one parity: 16384 slots * 2 u64 (256 KB)

typedef __attribute__((ext_vector_type(8))) short bf16x8;
typedef __attribute__((ext_vector_type(4))) float f32x4;

// ---------------------------------------------------------------------
// Agent-scope ops (validated R4-R11): relaxed sc-bit global ops serviced
// at the device coherence point (MALL) — coherent, uncached, no fences.
// R12/R13 lesson: pub-style rewritten addresses MUST use these; normal
// loads are only safe/fast for touch-once streams (xin).
// ---------------------------------------------------------------------
__device__ __forceinline__ unsigned aloadU32(const unsigned* p) {
  return __hip_atomic_load(p, __ATOMIC_RELAXED, __HIP_MEMORY_SCOPE_AGENT);
}
__device__ __forceinline__ unsigned long long aload64(
    const unsigned long long* p) {
  return __hip_atomic_load(p, __ATOMIC_RELAXED, __HIP_MEMORY_SCOPE_AGENT);
}
__device__ __forceinline__ void astore4(float* p, float a) {
  union { unsigned u; float f; } c; c.f = a;
  __hip_atomic_store((unsigned*)p, c.u, __ATOMIC_RELAXED,
                     __HIP_MEMORY_SCOPE_AGENT);
}
__device__ __forceinline__ void astoreU(unsigned long long* p,
                                        unsigned long long v) {
  __hip_atomic_store(p, v, __ATOMIC_RELAXED, __HIP_MEMORY_SCOPE_AGENT);
}

// bf16 split helpers
__device__ __forceinline__ unsigned bf16_rne(float x) {
  union { float f; unsigned u; } c; c.f = x;
  return (c.u + 0x7FFFu + ((c.u >> 16) & 1u)) >> 16;
}
__device__ __forceinline__ float bf16_to_f(unsigned b) {
  union { float f; unsigned u; } c; c.u = b << 16; return c.f;
}
__device__ __forceinline__ void cvt_pair(float x0, float x1,
                                         unsigned& hi, unsigned& lo) {
  unsigned h0 = bf16_rne(x0), h1 = bf16_rne(x1);
  float r0 = x0 - bf16_to_f(h0), r1 = x1 - bf16_to_f(h1);
  unsigned l0 = bf16_rne(r0), l1 = bf16_rne(r1);
  hi = h0 | (h1 << 16);
  lo = l0 | (l1 << 16);
}
__device__ __forceinline__ void cvt8(const float* s, uint4& hi, uint4& lo) {
  float4 a = *(const float4*)s;
  float4 b = *(const float4*)(s + 4);
  cvt_pair(a.x, a.y, hi.x, lo.x);
  cvt_pair(a.z, a.w, hi.y, lo.y);
  cvt_pair(b.x, b.y, hi.z, lo.z);
  cvt_pair(b.z, b.w, hi.w, lo.w);
}

// =====================================================================
// Kernel A (R14): MFMA split-bf16 xin GEMM.
// xin = x @ W_ih^T + b_ih + b_hh ; rows m<64 fold t=0:
// out[0] = 0.01*relu(xin[0]).
// Tile 128M x 128N, BK=32, grid (128 mb x 16 nb) = 2048 blocks.
// 256 thr / 4 waves in 2x2 quadrants (each wave 64x64).
// Split-bf16: x=hi+lo, W=hi+lo, terms hh+hl+lh (lo*lo dropped, <=2^-18).
// LDS frag-packed layout slot = tile*64 + lane (scan-proven,
// conflict-free ds_read_b128).  Global staging reads are 128B-contig
// per 4 threads.
// =====================================================================
__global__ __launch_bounds__(256) void xin_gemm(
    const float* __restrict__ x, const float* __restrict__ Wih,
    const float* __restrict__ bih, const float* __restrict__ bhh,
    float* __restrict__ out)
{
  __shared__ __align__(16) uint4 Xhi[512], Xlo[512];   // 8 KB each
  __shared__ __align__(16) uint4 Ghi[512], Glo[512];   // W_ih planes

  const int tid = threadIdx.x;
  const int nb = blockIdx.x & 15, mb = blockIdx.x >> 4;
  const int m0 = mb * 128, n0 = nb * 128;
  const int lane = tid & 63, wid = tid >> 6;
  const int wm = wid & 1, wn = wid >> 1;     // 64x64 quadrant
  const int fq = lane >> 4, fr = lane & 15;

  f32x4 acc[4][4];
  #pragma unroll
  for (int i = 0; i < 4; ++i)
    #pragma unroll
    for (int j = 0; j < 4; ++j) acc[i][j] = (f32x4){0.f, 0.f, 0.f, 0.f};

  for (int k0 = 0; k0 < I_DIM; k0 += 32) {
    __syncthreads();
    // stage both operands as hi/lo frags; thread covers frag f=tid, tid+256
    #pragma unroll
    for (int h = 0; h < 2; ++h) {
      const int f = tid + h * 256;
      const int r = f >> 2, o = f & 3;                 // row, k-octet
      const int s = (r >> 4) * 64 + o * 16 + (r & 15); // frag slot
      uint4 hi, lo;
      cvt8(&x[(size_t)(m0 + r) * I_DIM + k0 + o * 8], hi, lo);
      Xhi[s] = hi; Xlo[s] = lo;
      cvt8(&Wih[(size_t)(n0 + r) * I_DIM + k0 + o * 8], hi, lo);
      Ghi[s] = hi; Glo[s] = lo;
    }
    __syncthreads();

    uint4 ahi[4], alo[4];
    #pragma unroll
    for (int mt = 0; mt < 4; ++mt) {
      ahi[mt] = Xhi[(wm * 4 + mt) * 64 + lane];
      alo[mt] = Xlo[(wm * 4 + mt) * 64 + lane];
    }
    #pragma unroll
    for (int nt = 0; nt < 4; ++nt) {
      const uint4 bhv = Ghi[(wn * 4 + nt) * 64 + lane];
      const uint4 blv = Glo[(wn * 4 + nt) * 64 + lane];
      #pragma unroll
      for (int mt = 0; mt < 4; ++mt) {
        acc[mt][nt] = __builtin_amdgcn_mfma_f32_16x16x32_bf16(
            *(const bf16x8*)&ahi[mt], *(const bf16x8*)&bhv, acc[mt][nt],
            0, 0, 0);
        acc[mt][nt] = __builtin_amdgcn_mfma_f32_16x16x32_bf16(
            *(const bf16x8*)&ahi[mt], *(const bf16x8*)&blv, acc[mt][nt],
            0, 0, 0);
        acc[mt][nt] = __builtin_amdgcn_mfma_f32_16x16x32_bf16(
            *(const bf16x8*)&alo[mt], *(const bf16x8*)&bhv, acc[mt][nt],
            0, 0, 0);
      }
    }
  }

  // epilogue: + (b_ih + b_hh); rows m<64 are t=0 -> 0.01*relu; store.
  float bb[4];
  #pragma unroll
  for (int nt = 0; nt < 4; ++nt) {
    const int n = n0 + wn * 64 + nt * 16 + fr;
    bb[nt] = bih[n] + bhh[n];
  }
  #pragma unroll
  for (int mt = 0; mt < 4; ++mt)
    #pragma unroll
    for (int j = 0; j < 4; ++j) {
      const int m = m0 + wm * 64 + mt * 16 + fq * 4 + j;
      const bool fold = (m < B_DIM);
      #pragma unroll
      for (int nt = 0; nt < 4; ++nt) {
        const int n = n0 + wn * 64 + nt * 16 + fr;
        float v = acc[mt][nt][j] + bb[nt];
        if (fold) v = 0.01f * fmaxf(v, 0.f);
        out[(size_t)m * H_DIM + n] = v;
      }
    }
}

// =====================================================================
// Kernel B: BARRIER-FREE producer-consumer scan (R11, verbatim — best
// measured structure: 5.0 us/step, 1.28 ms).
// Block (bh,nb) consumes h rows [bh*32,+32) produced only by the 128
// blocks sharing bh; wave wid needs just 32 producers nb' in [wid*32,+32).
//   producer: publish h[t] frags -> vmcnt drain -> flag = t+1 (agent).
//   consumer wave: poll its 32 producer flags >= t, then GEMM.
// Double-buffer safety: entry at step t requires all group flags >= t.
// Pub A-frags read with relaxed AGENT loads (always coherent, no fence).
// =====================================================================
__global__ __launch_bounds__(256) void ctrnn_scan(
    const float* __restrict__ Whh, float* out,
    unsigned long long* __restrict__ pub, unsigned* slots)
{
  __shared__ __align__(16) uint4 Whi[4096];   // 64 KB
  __shared__ __align__(16) uint4 Wlo[4096];   // 64 KB
  __shared__ __align__(16) f32x4 Red[512];    // 8 KB
  __shared__ unsigned short Hs[32][16];       // 1 KB bf16 publish staging

  const int tid = threadIdx.x, bid = blockIdx.x;
  const int nb = bid & 127, bh = bid >> 7;
  const int n0 = nb * 16, b0 = bh * 32;

  const int lane = tid & 63, wid = tid >> 6;
  const int fq = lane >> 4, fr = lane & 15;

  // ---- stage W slice ONCE: rows n0..n0+16, all k, frag-packed hi/lo ----
  for (int s = tid; s < 4096; s += 256) {
    const int kcg = s >> 6, l = s & 63;
    const int n = n0 + (l & 15), k = kcg * 32 + (l >> 4) * 8;
    uint4 hi, lo;
    cvt8(&Whh[(size_t)n * H_DIM + k], hi, lo);
    Whi[s] = hi; Wlo[s] = lo;
  }

  // ---- ownership mapping (MFMA C layout: col=lane&15=n, row=b) ----
  const int bt = tid >> 7, jh = (tid >> 6) & 1, ln = tid & 63;
  const int rfr = ln & 15, rfq = ln >> 4;
  const int bl0 = bt * 16 + rfq * 4 + jh * 2;            // local b of 1st
  const size_t oa0 = (size_t)(b0 + bl0) * H_DIM + n0 + rfr;
  const size_t oa1 = oa0 + H_DIM;

  // fp32 h state in registers (h[0] = out[0], t=0 folded in xin_gemm)
  float h0 = out[oa0];
  float h1 = out[oa1];

  // ---- publish h[0] as bf16 frags to pub parity 0, then flag = 1 ----
  Hs[bl0][rfr]     = (unsigned short)bf16_rne(h0);
  Hs[bl0 + 1][rfr] = (unsigned short)bf16_rne(h1);
  __syncthreads();   // also covers W staging completion
  if (tid < 64) {
    const int b_l = tid & 31, h8 = tid >> 5;
    const uint4 frag = *(const uint4*)&Hs[b_l][h8 * 8];
    const size_t slot = (size_t)(nb * 2 + h8) * 64 + b0 + b_l;
    astoreU(&pub[slot * 2 + 0], ((const unsigned long long*)&frag)[0]);
    astoreU(&pub[slot * 2 + 1], ((const unsigned long long*)&frag)[1]);
  }
  asm volatile("s_waitcnt vmcnt(0)" ::: "memory");
  if (tid == 0)
    __hip_atomic_store(slots + (size_t)bid * 16, 1u, __ATOMIC_RELAXED,
                       __HIP_MEMORY_SCOPE_AGENT);

  // my wave's 32 producer flags: blocks (bh, wid*32 + 0..31)
  const unsigned* myflag =
      slots + (size_t)(bh * 128 + wid * 32 + (lane & 31)) * 16;

  const int baseA64 = (wid * 4096 + fq * 64 + b0 + fr) * 2;  // u64 units
  const int baseB = wid * 1024;                              // +kc*64+lane

  for (int t = 1; t < T_DIM; ++t) {
    // prefetch xin (normal load; touch-once line, latency hides in poll)
    const float xin0 = out[(size_t)t * BH + oa0];
    const float xin1 = out[(size_t)t * BH + oa1];
    asm volatile("" :: "v"(xin0), "v"(xin1));  // keep loads here

    // ---- per-wave flag poll: my 32 producers have published h[t-1] ----
    for (int it = 0; it < (1 << 17); ++it) {
      if (__all(aloadU32(myflag) >= (unsigned)t)) break;
      __builtin_amdgcn_s_sleep(1);
    }

    const unsigned long long* pr = pub + (size_t)((t - 1) & 1) * PUB_U64;

    // ---- GEMM: agent-load A-frags straight from MALL (no fence) ----
    f32x4 acc0 = {0.f, 0.f, 0.f, 0.f}, acc1 = {0.f, 0.f, 0.f, 0.f};
    #pragma unroll
    for (int kc = 0; kc < 16; ++kc) {
      union { unsigned long long u[2]; bf16x8 v; } a0c, a1c;
      a0c.u[0] = aload64(pr + baseA64 + kc * 512 + 0);
      a0c.u[1] = aload64(pr + baseA64 + kc * 512 + 1);
      a1c.u[0] = aload64(pr + baseA64 + kc * 512 + 32);
      a1c.u[1] = aload64(pr + baseA64 + kc * 512 + 33);
      const uint4 bh4 = Whi[baseB + kc * 64 + lane];
      const uint4 bl4 = Wlo[baseB + kc * 64 + lane];
      acc0 = __builtin_amdgcn_mfma_f32_16x16x32_bf16(
          a0c.v, *(const bf16x8*)&bh4, acc0, 0, 0, 0);
      acc0 = __builtin_amdgcn_mfma_f32_16x16x32_bf16(
          a0c.v, *(const bf16x8*)&bl4, acc0, 0, 0, 0);
      acc1 = __builtin_amdgcn_mfma_f32_16x16x32_bf16(
          a1c.v, *(const bf16x8*)&bh4, acc1, 0, 0, 0);
      acc1 = __builtin_amdgcn_mfma_f32_16x16x32_bf16(
          a1c.v, *(const bf16x8*)&bl4, acc1, 0, 0, 0);
    }

    // ---- cross-wave K reduce ----
    Red[(wid * 2 + 0) * 64 + lane] = acc0;
    Red[(wid * 2 + 1) * 64 + lane] = acc1;
    __syncthreads();

    float s0 = 0.f, s1 = 0.f;
    #pragma unroll
    for (int w = 0; w < 4; ++w) {
      const float2 p = *(const float2*)(
          (const char*)&Red[(w * 2 + bt) * 64 + ln] + jh * 8);
      s0 += p.x; s1 += p.y;
    }

    // ---- leaky-relu update (fp32 register state) ----
    h0 = 0.99f * h0 + 0.01f * fmaxf(xin0 + s0, 0.f);
    h1 = 0.99f * h1 + 0.01f * fmaxf(xin1 + s1, 0.f);

    // ---- output stores (not on the critical path) ----
    astore4(&out[(size_t)t * BH + oa0], h0);
    astore4(&out[(size_t)t * BH + oa1], h1);
    if (t == T_DIM - 1) {
      astore4(&out[(size_t)T_DIM * BH + oa0], h0);  // h_last
      astore4(&out[(size_t)T_DIM * BH + oa1], h1);
    }

    // ---- publish bf16 h[t] -> parity t&1, drain, flag = t+1 ----
    if (t < T_DIM - 1) {
      __syncthreads();   // Red reads done; safe to reuse Hs
      Hs[bl0][rfr]     = (unsigned short)bf16_rne(h0);
      Hs[bl0 + 1][rfr] = (unsigned short)bf16_rne(h1);
      __syncthreads();
      if (tid < 64) {
        const int b_l = tid & 31, h8 = tid >> 5;
        const uint4 frag = *(const uint4*)&Hs[b_l][h8 * 8];
        const size_t slot = (size_t)(nb * 2 + h8) * 64 + b0 + b_l;
        unsigned long long* pw =
            pub + (size_t)(t & 1) * PUB_U64 + slot * 2;
        astoreU(pw + 0, ((const unsigned long long*)&frag)[0]);
        astoreU(pw + 1, ((const unsigned long long*)&frag)[1]);
      }
      asm volatile("s_waitcnt vmcnt(0)" ::: "memory");
      if (tid == 0)
        __hip_atomic_store(slots + (size_t)bid * 16, (unsigned)(t + 1),
                           __ATOMIC_RELAXED, __HIP_MEMORY_SCOPE_AGENT);
    }
  }
}

// =====================================================================
extern "C" void kernel_launch(void* const* d_in, const int* in_sizes, int n_in,
                              void* d_out, int out_size, void* d_ws, size_t ws_size,
                              hipStream_t stream) {
  const float* x    = (const float*)d_in[0];
  const float* Wih  = (const float*)d_in[1];
  const float* bih  = (const float*)d_in[2];
  const float* Whh  = (const float*)d_in[3];
  const float* bhh  = (const float*)d_in[4];
  float* out = (float*)d_out;

  unsigned* slots = (unsigned*)d_ws;                          // 16 KB flags
  unsigned long long* pub =
      (unsigned long long*)((char*)d_ws + 32768);             // 512 KB

  hipMemsetAsync(d_ws, 0, 32768, stream);  // reset flags every call

  xin_gemm<<<dim3(2048), dim3(256), 0, stream>>>(x, Wih, bih, bhh, out);
  ctrnn_scan<<<dim3(NBLK), dim3(256), 0, stream>>>(Whh, out, pub, slots);
}